// Round 15
// baseline (294.506 us; speedup 1.0000x reference)
//
#include <hip/hip_runtime.h>
#include <hip/hip_bf16.h>
#include <cstddef>

#define N_NODES 50000
#define N_EDGES 1600000
#define IN_DIM 128
#define OUT_DIM 16
#define N_HEADS 8
#define QKV_DIM 128               // N_HEADS * OUT_DIM
#define HS_STRIDE 136             // padded LDS row stride for h staging (u16)
#define OS_STRIDE 392             // padded LDS row stride for out staging (u16)

#define SUBB 3125                 // N_NODES/16 sub-buckets (16 dst nodes each)
#define SUBB_PAD 3136             // 49 chunks * 64
#define NCHUNK 49
#define BCAP 1024                 // LDS cap per bucket in agg (lambda=512, >20 sigma)
#define BH_CHUNK 16384            // edges per scatter block
#define BH_BLOCKS 98              // 98*16384 = 1,605,632 >= 1.6M
#define GEMM_BLOCKS 782           // ceil(50000/64)
#define FUSED_BLOCKS (BH_BLOCKS + GEMM_BLOCKS)

typedef __hip_bfloat16 bf16;
typedef short bf16x8 __attribute__((ext_vector_type(8)));
typedef float f32x4  __attribute__((ext_vector_type(4)));

__device__ __forceinline__ float b2f(bf16 x) { return __bfloat162float(x); }

__device__ __forceinline__ float u16tof(unsigned int u) {
    unsigned int x = u << 16;
    float f;
    __builtin_memcpy(&f, &x, 4);
    return f;
}

__device__ __forceinline__ unsigned short f2bf(float v) {
    bf16 b = __float2bfloat16(v);
    unsigned short u;
    __builtin_memcpy(&u, &b, 2);
    return u;
}

__global__ __launch_bounds__(256) void sentinel_kernel(unsigned short* __restrict__ out, int n) {
    int i = blockIdx.x * 256 + threadIdx.x;
    if (i < n) out[i] = 0x42C8;
}

// ---------------------------------------------------------------------------
// prep: self-probe input dtype, publish flag, repack Wq|Wk|Wv into MFMA
// B-fragment order + fp32 bias vector. (byte-identical to R13/R14)
// ---------------------------------------------------------------------------
__global__ __launch_bounds__(256) void prep_kernel(
    const unsigned short* __restrict__ hraw,
    const void* __restrict__ Wqr, const void* __restrict__ bqr,
    const void* __restrict__ Wkr, const void* __restrict__ bkr,
    const void* __restrict__ Wvr, const void* __restrict__ bvr,
    int* __restrict__ flag,
    unsigned short* __restrict__ Wfrag, float* __restrict__ bias_f)
{
    __shared__ int red[256];
    const int t   = threadIdx.x;
    const int tid = blockIdx.x * 256 + t;

    int cnt = 0;
    for (int i = t; i < 8192; i += 256) {
        unsigned short u = hraw[i];
        int e = (u >> 7) & 0xFF;
        if (e == 0xFF || e > 0x85 || (e == 0 && (u & 0x7F) != 0)) cnt++;
    }
    red[t] = cnt;
    __syncthreads();
    for (int s = 128; s > 0; s >>= 1) {
        if (t < s) red[t] += red[t + s];
        __syncthreads();
    }
    const bool f32 = (red[0] > 100);
    if (blockIdx.x == 0 && t == 0) *flag = red[0];

    if (tid < 384) {
        int mat = tid >> 7, c = tid & 127;
        const void* bp = (mat == 0) ? bqr : (mat == 1) ? bkr : bvr;
        bias_f[tid] = f32 ? ((const float*)bp)[c] : b2f(((const bf16*)bp)[c]);
    }

    int l  = tid & 63;
    int s  = (tid >> 6) & 3;
    int nt = tid >> 8;
    int n  = nt * 16 + (l & 15);
    int k0 = s * 32 + (l >> 4) * 8;
    int mat = n >> 7, c = n & 127;
    const void* Wp = (mat == 0) ? Wqr : (mat == 1) ? Wkr : Wvr;

    unsigned short v[8];
#pragma unroll
    for (int j = 0; j < 8; ++j) {
        int k = k0 + j;
        float w = f32 ? ((const float*)Wp)[k * QKV_DIM + c]
                      : b2f(((const bf16*)Wp)[k * QKV_DIM + c]);
        v[j] = f2bf(w);
    }
    ushort4* o = (ushort4*)(Wfrag + (size_t)tid * 8);
    o[0] = make_ushort4(v[0], v[1], v[2], v[3]);
    o[1] = make_ushort4(v[4], v[5], v[6], v[7]);
}

// ---------------------------------------------------------------------------
// FUSED kernel: blocks [0,98) = scatter (wave-shfl scan, direct writes);
//               blocks [98,880) = MFMA projection GEMM.
// ---------------------------------------------------------------------------
__global__ __launch_bounds__(256) void fused_gs_kernel(
    const void* __restrict__ hraw,
    const unsigned short* __restrict__ Wfrag, const float* __restrict__ bias_f,
    const int* __restrict__ flag,
    unsigned short* __restrict__ Qt, unsigned short* __restrict__ KVt,
    const int* __restrict__ src, const int* __restrict__ dst,
    unsigned int* __restrict__ packed, unsigned int* __restrict__ offcnt)
{
    __shared__ __align__(16) unsigned char arena[64 * OS_STRIDE * 2];   // 50,176 B
    const int t = threadIdx.x;

    if (blockIdx.x < BH_BLOCKS) {
        // ----------------- scatter branch -----------------
        int* lcnt = (int*)arena;                    // 12,544 B (SUBB_PAD)
        int* sc   = (int*)(arena + 12544);          // 12,544 B inclusive scans
        int* ctot = (int*)(arena + 25088);          //    256 B chunk totals
        int* cpfx = (int*)(arena + 25344);          //    256 B chunk prefixes

        const int b    = blockIdx.x;
        const int base = b * BH_CHUNK;
        const int nb   = min(N_EDGES - base, BH_CHUNK);
        const int wave = t >> 6;
        const int lane = t & 63;

        for (int i = t; i < SUBB_PAD; i += 256) lcnt[i] = 0;
        __syncthreads();

        // pass 1: count buckets
        for (int i = t; i < nb; i += 256)
            atomicAdd(&lcnt[dst[base + i] >> 4], 1);
        __syncthreads();

        // wave-level scan: wave w handles chunks w, w+4, ... (49 chunks of 64)
        for (int c = wave; c < NCHUNK; c += 4) {
            int i = c * 64 + lane;
            int x = (i < SUBB) ? lcnt[i] : 0;
            int v = x;
#pragma unroll
            for (int s = 1; s < 64; s <<= 1) {
                int a = __shfl_up(v, s);
                if (lane >= s) v += a;
            }
            sc[i] = v;                       // inclusive within chunk
            if (lane == 63) ctot[c] = v;     // chunk total
        }
        __syncthreads();

        // wave 0: scan the 49 chunk totals -> exclusive chunk prefixes
        if (wave == 0) {
            int x = (lane < NCHUNK) ? ctot[lane] : 0;
            int v = x;
#pragma unroll
            for (int s = 1; s < 64; s <<= 1) {
                int a = __shfl_up(v, s);
                if (lane >= s) v += a;
            }
            if (lane < NCHUNK) cpfx[lane] = v - x;
        }
        __syncthreads();

        // emit offcnt; seed lcnt with absolute in-block offsets (cursors)
        for (int i = t; i < SUBB_PAD; i += 256) {
            int x    = lcnt[i];
            int excl = cpfx[i >> 6] + sc[i] - x;
            if (i < SUBB)
                offcnt[(size_t)b * SUBB + i] =
                    ((unsigned int)excl << 16) | (unsigned int)x;
            lcnt[i] = excl;
        }
        __syncthreads();

        // pass 2: direct scattered writes within own 64 KB region
        for (int i = t; i < nb; i += 256) {
            int d  = dst[base + i];
            int bk = d >> 4;
            int pos = atomicAdd(&lcnt[bk], 1);
            packed[base + pos] = (unsigned int)src[base + i] | ((unsigned int)(d & 15) << 16);
        }

    } else {
        // ----------------- gemm branch -----------------
        unsigned short* smem = (unsigned short*)arena;

        const bool f32 = (*flag > 100);
        const int m0 = (blockIdx.x - BH_BLOCKS) * 64;

#pragma unroll
        for (int it = 0; it < 8; ++it) {
            int idx = it * 1024 + t * 4;
            int r = idx >> 7, k = idx & 127;
            int row = m0 + r;
            ushort4 w4 = make_ushort4(0, 0, 0, 0);
            if (row < N_NODES) {
                if (f32) {
                    float4 v4 = ((const float4*)hraw)[(size_t)row * 32 + (k >> 2)];
                    w4 = make_ushort4(f2bf(v4.x), f2bf(v4.y), f2bf(v4.z), f2bf(v4.w));
                } else {
                    uint2 u = ((const uint2*)hraw)[(size_t)row * 32 + (k >> 2)];
                    w4 = make_ushort4((unsigned short)(u.x & 0xffffu), (unsigned short)(u.x >> 16),
                                      (unsigned short)(u.y & 0xffffu), (unsigned short)(u.y >> 16));
                }
            }
            *(ushort4*)&smem[r * HS_STRIDE + k] = w4;
        }
        __syncthreads();

        const int lane = t & 63;
        const int wave = t >> 6;
        const int qd   = lane >> 4;
        const int ln15 = lane & 15;

        bf16x8 afr[4][4];
#pragma unroll
        for (int ms = 0; ms < 4; ++ms)
#pragma unroll
            for (int s = 0; s < 4; ++s)
                afr[ms][s] = *(const bf16x8*)&smem[(ms * 16 + ln15) * HS_STRIDE + s * 32 + qd * 8];

        __syncthreads();   // smem reused for output staging

#pragma unroll
        for (int i = 0; i < 6; ++i) {
            const int nt  = wave + i * 4;
            const int col = nt * 16 + ln15;
            const float bs = bias_f[col];
            const int mat = col >> 7, c127 = col & 127;
            const int ocol = (mat == 0) ? c127
                           : 128 + 8 * (c127 >> 2) + (c127 & 3) + ((mat == 2) ? 4 : 0);

            bf16x8 bfr[4];
#pragma unroll
            for (int s = 0; s < 4; ++s)
                bfr[s] = *(const bf16x8*)(Wfrag + ((size_t)(nt * 4 + s) * 64 + lane) * 8);

#pragma unroll
            for (int ms = 0; ms < 4; ++ms) {
                f32x4 acc = {0.f, 0.f, 0.f, 0.f};
#pragma unroll
                for (int s = 0; s < 4; ++s)
                    acc = __builtin_amdgcn_mfma_f32_16x16x32_bf16(afr[ms][s], bfr[s], acc, 0, 0, 0);
#pragma unroll
                for (int r = 0; r < 4; ++r) {
                    int rl = ms * 16 + qd * 4 + r;
                    smem[rl * OS_STRIDE + ocol] = f2bf(acc[r] + bs);
                }
            }
        }
        __syncthreads();

        for (int q = t; q < 1024; q += 256) {
            int row = q >> 4, c = q & 15;
            int grow = m0 + row;
            if (grow < N_NODES)
                ((uint4*)Qt)[grow * 16 + c] = *(const uint4*)&smem[row * OS_STRIDE + c * 8];
        }
        for (int q = t; q < 2048; q += 256) {
            int row = q >> 5, g = q & 31;
            int grow = m0 + row;
            if (grow < N_NODES)
                ((uint4*)KVt)[grow * 32 + g] = *(const uint4*)&smem[row * OS_STRIDE + 128 + g * 8];
        }
    }
}

// ---------------------------------------------------------------------------
// Fused run-gather + bucket sort + aggregation (R13 structure, 98 runs).
// ---------------------------------------------------------------------------
__global__ __launch_bounds__(256) void bucket_agg_kernel(
    const unsigned short* __restrict__ Qt, const unsigned short* __restrict__ KVt,
    const unsigned int* __restrict__ packed, const unsigned int* __restrict__ offcnt,
    const int* __restrict__ flag, void* __restrict__ out)
{
    __shared__ unsigned int   lds_pk[BCAP];     // 4 KB (also scan scratch)
    __shared__ unsigned short lds_src[BCAP];    // 2 KB
    __shared__ int runoff[BH_BLOCKS], runcnt[BH_BLOCKS], runpfx[BH_BLOCKS];
    __shared__ int cnt16[16], base16[16], cur16[16];
    __shared__ int nb_s;

    const int sb = blockIdx.x;
    const int t  = threadIdx.x;

    if (t < 16) { cnt16[t] = 0; cur16[t] = 0; }
    if (t < BH_BLOCKS) {
        unsigned int oc = offcnt[(size_t)t * SUBB + sb];
        runoff[t] = t * BH_CHUNK + (int)(oc >> 16);
        runcnt[t] = (int)(oc & 0xffffu);
    }
    __syncthreads();

    {
        int* sm = (int*)lds_pk;
        int x = (t < BH_BLOCKS) ? runcnt[t] : 0;
        int v = x;
        sm[t] = v;
        __syncthreads();
        for (int s = 1; s < 256; s <<= 1) {
            int a = (t >= s) ? sm[t - s] : 0;
            __syncthreads();
            v += a;
            sm[t] = v;
            __syncthreads();
        }
        if (t < BH_BLOCKS) runpfx[t] = v - x;
        if (t == 255) nb_s = v;
        __syncthreads();
    }
    const int nb = min(nb_s, BCAP);

    for (int r = t; r < BH_BLOCKS; r += 256) {
        int ro = runoff[r], rc = runcnt[r], rp = runpfx[r];
        for (int j = 0; j < rc; ++j) {
            int dpos = rp + j;
            if (dpos < BCAP) {
                unsigned int pk = packed[ro + j];
                lds_pk[dpos] = pk;
                atomicAdd(&cnt16[(pk >> 16) & 15], 1);
            }
        }
    }
    __syncthreads();
    if (t == 0) {
        int acc = 0;
#pragma unroll
        for (int i = 0; i < 16; ++i) { base16[i] = acc; acc += cnt16[i]; }
    }
    __syncthreads();
    for (int j = t; j < nb; j += 256) {
        unsigned int pk = lds_pk[j];
        int dl = (pk >> 16) & 15;
        int pos = base16[dl] + atomicAdd(&cur16[dl], 1);
        lds_src[pos] = (unsigned short)(pk & 0xffffu);
    }
    __syncthreads();

    const int wave = t >> 6;
    const int lane = t & 63;
    const int half = lane >> 5;
    const int hl   = lane & 31;
    const uint4* KV4 = (const uint4*)KVt;
    const bool of32 = (*flag > 100);

    for (int dl = wave; dl < 16; dl += 4) {
        const int d = sb * 16 + dl;
        uint2 qw = ((const uint2*)Qt)[d * 32 + hl];
        const float q0 = u16tof(qw.x & 0xffffu), q1 = u16tof(qw.x >> 16);
        const float q2 = u16tof(qw.y & 0xffffu), q3 = u16tof(qw.y >> 16);
        const int off = base16[dl];
        const int n   = cnt16[dl];

        float a0 = 0.f, a1 = 0.f, a2 = 0.f, a3 = 0.f, zz = 0.f;

#define CONSUME(KV, SCMASK)                                                     \
        {                                                                       \
            float p = fmaf(u16tof((KV).x & 0xffffu), q0,                        \
                      fmaf(u16tof((KV).x >> 16), q1,                            \
                      fmaf(u16tof((KV).y & 0xffffu), q2,                        \
                           u16tof((KV).y >> 16) * q3)));                        \
            p += __shfl_xor(p, 1);                                              \
            p += __shfl_xor(p, 2);                                              \
            float sc = __expf(__builtin_amdgcn_fmed3f(p * 0.25f, -5.f, 5.f));   \
            sc *= (SCMASK);                                                     \
            a0 = fmaf(u16tof((KV).z & 0xffffu), sc, a0);                        \
            a1 = fmaf(u16tof((KV).z >> 16),     sc, a1);                        \
            a2 = fmaf(u16tof((KV).w & 0xffffu), sc, a2);                        \
            a3 = fmaf(u16tof((KV).w >> 16),     sc, a3);                        \
            zz += sc;                                                           \
        }

        int j = 0;
        for (; j + 8 <= n; j += 8) {
            int e[4];
#pragma unroll
            for (int u = 0; u < 4; ++u) e[u] = lds_src[off + j + 2 * u + half];
            uint4 kv[4];
#pragma unroll
            for (int u = 0; u < 4; ++u) kv[u] = KV4[e[u] * 32 + hl];
#pragma unroll
            for (int u = 0; u < 4; ++u) CONSUME(kv[u], 1.f)
        }
        for (; j + 2 <= n; j += 2) {
            int e = lds_src[off + j + half];
            uint4 kv = KV4[e * 32 + hl];
            CONSUME(kv, 1.f)
        }
        if (j < n) {
            int e = lds_src[off + j];
            uint4 kv = KV4[e * 32 + hl];
            CONSUME(kv, (half == 0) ? 1.f : 0.f)
        }
#undef CONSUME

        a0 += __shfl_xor(a0, 32);
        a1 += __shfl_xor(a1, 32);
        a2 += __shfl_xor(a2, 32);
        a3 += __shfl_xor(a3, 32);
        zz += __shfl_xor(zz, 32);

        const float inv = 1.f / (zz + 1e-6f);
        const float r0 = a0 * inv, r1 = a1 * inv, r2 = a2 * inv, r3 = a3 * inv;

        if (half == 0) {
            if (of32) {
                ((float4*)out)[d * 32 + hl] = make_float4(r0, r1, r2, r3);
            } else {
                unsigned int w0 = ((unsigned int)f2bf(r1) << 16) | f2bf(r0);
                unsigned int w1 = ((unsigned int)f2bf(r3) << 16) | f2bf(r2);
                ((uint2*)out)[d * 32 + hl] = make_uint2(w0, w1);
            }
        }
    }
}

// ---------------------------------------------------------------------------
extern "C" void kernel_launch(void* const* d_in, const int* in_sizes, int n_in,
                              void* d_out, int out_size, void* d_ws, size_t ws_size,
                              hipStream_t stream)
{
    const void* h  = d_in[0];
    const void* Wq = d_in[1];
    const void* bq = d_in[2];
    const void* Wk = d_in[3];
    const void* bk = d_in[4];
    const void* Wv = d_in[5];
    const void* bv = d_in[6];
    const int*  src = (const int*)d_in[7];
    const int*  dst = (const int*)d_in[8];

    const size_t NQ = (size_t)N_NODES * QKV_DIM;   // 6,400,000
    const size_t WFRAG_N = 24 * 4 * 64 * 8;        // 49,152
    const size_t PACKED_N = (size_t)BH_BLOCKS * BH_CHUNK;   // 1,605,632
    const size_t OFFCNT_N = (size_t)BH_BLOCKS * SUBB;       // 306,250

    const size_t need = 3 * NQ * 2 + WFRAG_N * 2 + 384 * 4 + 64
                      + PACKED_N * 4 + OFFCNT_N * 4;

    if (ws_size < need) {
        sentinel_kernel<<<(out_size + 255) / 256, 256, 0, stream>>>((unsigned short*)d_out, out_size);
        return;
    }

    unsigned short* Qt  = (unsigned short*)d_ws;
    unsigned short* KVt = Qt + NQ;
    unsigned short* Wfrag = KVt + 2 * NQ;
    float* bias_f = (float*)(Wfrag + WFRAG_N);
    int* flag     = (int*)(bias_f + 384);
    unsigned int* packed = (unsigned int*)(flag + 16);
    unsigned int* offcnt = packed + PACKED_N;

    prep_kernel<<<24, 256, 0, stream>>>((const unsigned short*)h,
        Wq, bq, Wk, bk, Wv, bv, flag, Wfrag, bias_f);

    fused_gs_kernel<<<FUSED_BLOCKS, 256, 0, stream>>>(h, Wfrag, bias_f, flag,
        Qt, KVt, src, dst, packed, offcnt);

    bucket_agg_kernel<<<SUBB, 256, 0, stream>>>(Qt, KVt, packed, offcnt, flag, d_out);
}